// Round 11
// baseline (353.008 us; speedup 1.0000x reference)
//
#include <hip/hip_runtime.h>

#define ALPHA 0.2f
#define EPS 1e-16f

static constexpr int F_IN = 256;
static constexpr int F_OUT = 128;
static constexpr int HEADS = 4;
static constexpr int COLS = HEADS * F_OUT; // 512

typedef __bf16 bf16x8 __attribute__((ext_vector_type(8)));
typedef float f32x4 __attribute__((ext_vector_type(4)));

static __device__ __forceinline__ unsigned short f2bf(float f) {
  unsigned int u = __float_as_uint(f);
  unsigned int r = (u + 0x7FFFu + ((u >> 16) & 1u)) >> 16;  // RN-even
  return (unsigned short)r;
}
static __device__ __forceinline__ float bf_lo(unsigned int u) {
  return __uint_as_float(u << 16);
}
static __device__ __forceinline__ float bf_hi(unsigned int u) {
  return __uint_as_float(u & 0xFFFF0000u);
}

// ---------------- K2: 128x128 MFMA GEMM, LDS-FREE (direct global fragments) ---
// Fragment fact (m89-verified layout): for mfma_f32_16x16x32_bf16 the A-frag of
// lane l is A[row_tile + (l&15)][k0 + (l>>4)*8 .. +7] — 8 consecutive elems.
// So fragments load straight from global f32 with in-register RNE cvt; no LDS,
// no main-loop barriers, no bank conflicts.
// Blocks >= Tg: edge-rank side pass (hidden under gemm).
// rec[n] (32B): bytes 0..15 = sdst (4 f32); bytes 16..31 = 8 bf16 scales.
// Hq row layout (per 64-col block b): u32 at byte 64b+4k holds cols {0,16,32,48}+k.
__global__ __launch_bounds__(256, 2) void k_gemm_q(const float* __restrict__ A,
                                                   const float* __restrict__ Wf,
                                                   unsigned char* __restrict__ Hq,
                                                   unsigned char* __restrict__ rec,
                                                   float* __restrict__ ssrc,
                                                   const float* __restrict__ Av, int N, int Tg,
                                                   const int* __restrict__ src,
                                                   int* __restrict__ cnt,
                                                   unsigned short* __restrict__ rank, int E) {
  if ((int)blockIdx.x >= Tg) {   // ---- rank side-blocks (1024 blocks) ----
    int i = ((int)blockIdx.x - Tg) * 256 + threadIdx.x;
    const int stride = 1024 * 256;
    for (; i < E; i += stride) rank[i] = (unsigned short)atomicAdd(&cnt[src[i]], 1);
    return;
  }
  __shared__ float sS[128], sD[128];
  // --- bijective XCD chunking over the Tg gemm blocks (col-fastest) ---
  const int T = Tg;
  const int q8 = T >> 3, r8 = T & 7;
  const int xcd = blockIdx.x & 7, ii = blockIdx.x >> 3;
  const int gp = (xcd < r8) ? xcd * (q8 + 1) + ii
                            : r8 * (q8 + 1) + (xcd - r8) * q8 + ii;
  const int by = gp >> 2;                  // row-tile
  const int bx = gp & 3;                   // 128-col block == head
  const int t = threadIdx.x;
  const int w = t >> 6, l = t & 63;
  const int wr = w >> 1, wc = w & 1;       // 2x2 wave grid, each 64x64
  const int m0 = by << 7, n0 = bx << 7;
  const int lrow = l & 15;
  const int kq = (l >> 4) << 3;            // lane's k-offset (f32 elems)
  // per-fragment row pointers (A rows clamped; stores guarded later)
  const float* arow[4];
  const float* wrow[4];
#pragma unroll
  for (int mi = 0; mi < 4; ++mi) {
    int r = m0 + (wr << 6) + (mi << 4) + lrow;
    if (r >= N) r = N - 1;
    arow[mi] = A + (size_t)r * F_IN + kq;
  }
#pragma unroll
  for (int ni = 0; ni < 4; ++ni)
    wrow[ni] = Wf + (size_t)(n0 + (wc << 6) + (ni << 4) + lrow) * F_IN + kq;

  f32x4 acc[4][4] = {};
  for (int k0 = 0; k0 < F_IN; k0 += 32) {
    bf16x8 af[4], bf_[4];
#pragma unroll
    for (int mi = 0; mi < 4; ++mi) {
      const float4 p0 = *(const float4*)(arow[mi] + k0);
      const float4 p1 = *(const float4*)(arow[mi] + k0 + 4);
      af[mi][0] = (__bf16)p0.x; af[mi][1] = (__bf16)p0.y;
      af[mi][2] = (__bf16)p0.z; af[mi][3] = (__bf16)p0.w;
      af[mi][4] = (__bf16)p1.x; af[mi][5] = (__bf16)p1.y;
      af[mi][6] = (__bf16)p1.z; af[mi][7] = (__bf16)p1.w;
    }
#pragma unroll
    for (int ni = 0; ni < 4; ++ni) {
      const float4 p0 = *(const float4*)(wrow[ni] + k0);
      const float4 p1 = *(const float4*)(wrow[ni] + k0 + 4);
      bf_[ni][0] = (__bf16)p0.x; bf_[ni][1] = (__bf16)p0.y;
      bf_[ni][2] = (__bf16)p0.z; bf_[ni][3] = (__bf16)p0.w;
      bf_[ni][4] = (__bf16)p1.x; bf_[ni][5] = (__bf16)p1.y;
      bf_[ni][6] = (__bf16)p1.z; bf_[ni][7] = (__bf16)p1.w;
    }
#pragma unroll
    for (int mi = 0; mi < 4; ++mi)
#pragma unroll
      for (int ni = 0; ni < 4; ++ni)
        acc[mi][ni] = __builtin_amdgcn_mfma_f32_16x16x32_bf16(af[mi], bf_[ni], acc[mi][ni], 0, 0, 0);
  }
  // ---- score epilogue: s_src/s_dst for head bx from f32 accumulators ----
  {
    float as_[4], ad_[4];
#pragma unroll
    for (int ni = 0; ni < 4; ++ni) {
      const int f = (wc << 6) + (ni << 4) + lrow;
      as_[ni] = Av[bx * 256 + f];
      ad_[ni] = Av[bx * 256 + 128 + f];
    }
#pragma unroll
    for (int mi = 0; mi < 4; ++mi)
#pragma unroll
      for (int r = 0; r < 4; ++r) {
        float ds_ = 0.f, dd_ = 0.f;
#pragma unroll
        for (int ni = 0; ni < 4; ++ni) {
          ds_ = fmaf(acc[mi][ni][r], as_[ni], ds_);
          dd_ = fmaf(acc[mi][ni][r], ad_[ni], dd_);
        }
#pragma unroll
        for (int m = 1; m < 16; m <<= 1) {
          ds_ += __shfl_xor(ds_, m);
          dd_ += __shfl_xor(dd_, m);
        }
        if (wc == 0 && (l & 15) == 0) {
          const int rl = (wr << 6) + (mi << 4) + ((l >> 4) << 2) + r;
          sS[rl] = ds_; sD[rl] = dd_;
        }
      }
    __syncthreads();
    if (wc == 1) {
#pragma unroll
      for (int mi = 0; mi < 4; ++mi)
#pragma unroll
        for (int r = 0; r < 4; ++r) {
          float ds_ = 0.f, dd_ = 0.f;
#pragma unroll
          for (int ni = 0; ni < 4; ++ni) {
            ds_ = fmaf(acc[mi][ni][r], as_[ni], ds_);
            dd_ = fmaf(acc[mi][ni][r], ad_[ni], dd_);
          }
#pragma unroll
          for (int m = 1; m < 16; m <<= 1) {
            ds_ += __shfl_xor(ds_, m);
            dd_ += __shfl_xor(dd_, m);
          }
          if ((l & 15) == 0) {
            const int rl = (wr << 6) + (mi << 4) + ((l >> 4) << 2) + r;
            const int row = m0 + rl;
            if (row < N) {
              ssrc[row * 4 + bx] = sS[rl] + ds_;
              *(float*)&rec[(size_t)row * 32 + (bx << 2)] = sD[rl] + dd_;
            }
          }
        }
    }
  }
  // ---- quant epilogue: per-row absmax per 64-col block, excess-128 int8 ----
  const int bxg = (bx << 1) + wc;          // global 64-col block 0..7
#pragma unroll
  for (int mi = 0; mi < 4; ++mi)
#pragma unroll
    for (int r = 0; r < 4; ++r) {
      float mx = 0.f;
#pragma unroll
      for (int ni = 0; ni < 4; ++ni) mx = fmaxf(mx, fabsf(acc[mi][ni][r]));
#pragma unroll
      for (int m = 1; m < 16; m <<= 1) mx = fmaxf(mx, __shfl_xor(mx, m));
      const int row = m0 + (wr << 6) + (mi << 4) + ((l >> 4) << 2) + r;
      if (row < N) {
        const float inv = (mx > 0.f) ? 127.f / mx : 0.f;
        if ((l & 15) == 0)
          *(unsigned short*)&rec[(size_t)row * 32 + 16 + (bxg << 1)] = f2bf(mx * (1.f / 127.f));
        unsigned int pk = 0;
#pragma unroll
        for (int ni = 0; ni < 4; ++ni) {
          float tq = fminf(fmaxf(rintf(acc[mi][ni][r] * inv), -127.f), 127.f);
          pk |= ((unsigned int)(((int)tq + 128) & 255)) << (8 * ni);  // excess-128
        }
        *(unsigned int*)&Hq[(size_t)row * 512 + (bxg << 6) + ((l & 15) << 2)] = pk;
      }
    }
}

// ---------------- scans over cnt -> off ---------------------------------------
__global__ __launch_bounds__(1024) void k_scan1(int* __restrict__ cnt,
                                                int* __restrict__ bsum, int N) {
  __shared__ int ws[16];
  const int t = threadIdx.x, g = blockIdx.x * 1024 + t;
  const int lane = t & 63, w = t >> 6;
  int v = (g < N) ? cnt[g] : 0;
#pragma unroll
  for (int o = 1; o < 64; o <<= 1) {
    const int y = __shfl_up(v, o);
    if (lane >= o) v += y;
  }
  if (lane == 63) ws[w] = v;
  __syncthreads();
  if (w == 0) {
    int s = (lane < 16) ? ws[lane] : 0;
#pragma unroll
    for (int o = 1; o < 16; o <<= 1) {
      const int y = __shfl_up(s, o);
      if (lane >= o) s += y;
    }
    if (lane < 16) ws[lane] = s;
  }
  __syncthreads();
  v += (w > 0) ? ws[w - 1] : 0;
  if (g < N) cnt[g] = v;                  // in-place inclusive within chunk
  if (t == 1023) bsum[blockIdx.x] = v;
}

// fused: every block scans bsum locally (nb <= 256), then adds carry
__global__ __launch_bounds__(1024) void k_scan3(const int* __restrict__ part,
                                                const int* __restrict__ bsum,
                                                int* __restrict__ off, int N, int nb) {
  __shared__ int sbuf[256];
  const int t = threadIdx.x;
  if (t < 64) {
    int carry = 0;
    for (int base = 0; base < nb; base += 64) {
      int v = (base + t < nb) ? bsum[base + t] : 0;
#pragma unroll
      for (int o = 1; o < 64; o <<= 1) {
        const int y = __shfl_up(v, o);
        if (t >= o) v += y;
      }
      v += carry;
      if (base + t < nb) sbuf[base + t] = v;
      carry = __shfl(v, 63);
    }
  }
  __syncthreads();
  const int g = blockIdx.x * 1024 + t;
  if (g == 0) off[0] = 0;
  if (g < N) off[g + 1] = part[g] + (blockIdx.x ? sbuf[blockIdx.x - 1] : 0);
}

// ---------------- K3: scatter (no atomics; u16 dst) ---------------------------
__global__ void k_scatter(const int* __restrict__ src, const int* __restrict__ dst,
                          const int* __restrict__ off, const unsigned short* __restrict__ rank,
                          unsigned short* __restrict__ csr_dst, int E) {
  int i = blockIdx.x * blockDim.x + threadIdx.x;
  const int stride = gridDim.x * blockDim.x;
  for (; i < E; i += stride)
    csr_dst[off[src[i]] + rank[i]] = (unsigned short)dst[i];
}

// ---------------- K4: fused softmax + SpMM, excess-128 int8 -------------------
__global__ __launch_bounds__(256) void k_spmm(const uint2* __restrict__ Hq2,
    const float4* __restrict__ ssrc4, const unsigned char* __restrict__ rec,
    const int* __restrict__ off, const unsigned short* __restrict__ csr_dst,
    const float* __restrict__ bias, float* __restrict__ out, int N) {
  __shared__ float wbuf[4][8][72];   // [wave][col-block][edge], w[h]*scl[d][b]
  __shared__ int   ibuf[4][64];
  const int wv = threadIdx.x >> 6;
  const int lane = threadIdx.x & 63;
  const int n = (blockIdx.x << 2) + wv;
  if (n >= N) return;                 // wave-private LDS, no barriers
  const int hg = lane >> 4;           // head of this lane
  const int b8 = lane >> 3;           // 64-col block of this lane
  const float4 ss4 = ssrc4[n];
  float den4[4] = {};
  float acc[8] = {};
  float sw = 0.f;                     // sum of this lane's scaled weights
  const int beg = off[n], end = off[n + 1];
  for (int c0 = beg; c0 < end; c0 += 64) {
    const int cnt = min(64, end - c0);
    if (lane < cnt) {                 // -------- phase A --------
      const int d = csr_dst[c0 + lane];          // coalesced u16
      ibuf[wv][lane] = d << 6;                   // row base in uint2 units
      const float4 sd4 = *(const float4*)&rec[(size_t)d * 32];       // one line:
      const uint4  sc  = *(const uint4*)&rec[(size_t)d * 32 + 16];   // sdst+scales
      float e0 = ss4.x + sd4.x; e0 = fmaxf(e0, ALPHA * e0);
      float e1 = ss4.y + sd4.y; e1 = fmaxf(e1, ALPHA * e1);
      float e2 = ss4.z + sd4.z; e2 = fmaxf(e2, ALPHA * e2);
      float e3 = ss4.w + sd4.w; e3 = fmaxf(e3, ALPHA * e3);
      const float w0 = __expf(e0), w1 = __expf(e1), w2 = __expf(e2), w3 = __expf(e3);
      den4[0] += w0; den4[1] += w1; den4[2] += w2; den4[3] += w3;
      wbuf[wv][0][lane] = w0 * bf_lo(sc.x); wbuf[wv][1][lane] = w0 * bf_hi(sc.x);
      wbuf[wv][2][lane] = w1 * bf_lo(sc.y); wbuf[wv][3][lane] = w1 * bf_hi(sc.y);
      wbuf[wv][4][lane] = w2 * bf_lo(sc.z); wbuf[wv][5][lane] = w2 * bf_hi(sc.z);
      wbuf[wv][6][lane] = w3 * bf_lo(sc.w); wbuf[wv][7][lane] = w3 * bf_hi(sc.w);
    }
#pragma unroll 8
    for (int j = 0; j < cnt; ++j) {   // -------- phase B --------
      const float wgt = wbuf[wv][b8][j];         // LDS broadcast (scaled)
      const int db = ibuf[wv][j];                // LDS broadcast
      const uint2 q = Hq2[db + lane];            // 8B gather, 512B/row/wave
      sw += wgt;
      acc[0] = fmaf(wgt, (float)(q.x & 0xffu),         acc[0]);
      acc[1] = fmaf(wgt, (float)((q.x >> 8) & 0xffu),  acc[1]);
      acc[2] = fmaf(wgt, (float)((q.x >> 16) & 0xffu), acc[2]);
      acc[3] = fmaf(wgt, (float)(q.x >> 24),           acc[3]);
      acc[4] = fmaf(wgt, (float)(q.y & 0xffu),         acc[4]);
      acc[5] = fmaf(wgt, (float)((q.y >> 8) & 0xffu),  acc[5]);
      acc[6] = fmaf(wgt, (float)((q.y >> 16) & 0xffu), acc[6]);
      acc[7] = fmaf(wgt, (float)(q.y >> 24),           acc[7]);
    }
  }
#pragma unroll
  for (int k = 0; k < 4; ++k)
#pragma unroll
    for (int m = 1; m < 64; m <<= 1) den4[k] += __shfl_xor(den4[k], m);
  const float r = 1.f / (den4[hg] + EPS);
  const float corr = 128.f * sw;      // undo excess-128 bias
#pragma unroll
  for (int i = 0; i < 8; ++i) acc[i] = (acc[i] - corr) * r;
#pragma unroll
  for (int i = 0; i < 8; ++i) {       // sum the 4 heads (same feature at l^16,l^32)
    acc[i] += __shfl_xor(acc[i], 16);
    acc[i] += __shfl_xor(acc[i], 32);
  }
  if (lane < 16) {
    // permuted layout: acc[i] = feature 64*((lane>>3)&1) + (i&3)*16 + 2*(lane&7) + (i>>2)
    const int base = ((lane >> 3) & 1) * 64 + ((lane & 7) << 1);
#pragma unroll
    for (int k = 0; k < 4; ++k) {
      const float2 b2 = *(const float2*)&bias[base + k * 16];
      *(float2*)&out[(size_t)n * F_OUT + base + k * 16] =
          make_float2(0.25f * acc[k] + b2.x, 0.25f * acc[k + 4] + b2.y);
    }
  }
}

// ---------------- launch -------------------------------------------------------
extern "C" void kernel_launch(void* const* d_in, const int* in_sizes, int n_in,
                              void* d_out, int out_size, void* d_ws, size_t ws_size,
                              hipStream_t stream) {
  const float* H    = (const float*)d_in[0];
  const int*   ei   = (const int*)d_in[1];
  const float* W    = (const float*)d_in[2];   // [4,128,256] == [512,256]
  const float* a    = (const float*)d_in[3];   // [4,256]
  const float* bias = (const float*)d_in[4];   // [128]
  const int N = in_sizes[0] / F_IN;
  const int E = in_sizes[1] / 2;
  const int* src = ei;
  const int* dst = ei + E;

  char* ws = (char*)d_ws;
  size_t o = 0;
  auto alloc = [&](size_t bytes) -> void* {
    void* p = ws + o;
    o = (o + bytes + 255) & ~(size_t)255;
    return p;
  };
  unsigned char*  Hq  = (unsigned char*)alloc((size_t)N * COLS);        // 25.6 MB int8
  float* ssrc = (float*)alloc((size_t)N * HEADS * sizeof(float));
  unsigned char* rec = (unsigned char*)alloc((size_t)N * 32);           // 1.6 MB packed
  int*   cnt  = (int*)alloc((size_t)N * sizeof(int));
  int*   off  = (int*)alloc(((size_t)N + 1) * sizeof(int));
  unsigned short* csr = (unsigned short*)alloc((size_t)E * sizeof(unsigned short));
  unsigned short* rank = (unsigned short*)alloc((size_t)E * sizeof(unsigned short));
  const int nb = (N + 1023) / 1024;
  int*   bsum = (int*)alloc((size_t)nb * sizeof(int));

  hipMemsetAsync(cnt, 0, (size_t)N * sizeof(int), stream);

  const int nb128 = (N + 127) / 128;
  const int Tg = 4 * nb128;
  k_gemm_q<<<Tg + 1024, 256, 0, stream>>>(H, W, Hq, rec, ssrc, a, N, Tg,
                                          src, cnt, rank, E);
  k_scan1<<<nb, 1024, 0, stream>>>(cnt, bsum, N);
  k_scan3<<<nb, 1024, 0, stream>>>(cnt, bsum, off, N, nb);
  k_scatter<<<1024, 256, 0, stream>>>(src, dst, off, rank, csr, E);
  k_spmm<<<(N + 3) / 4, 256, 0, stream>>>((const uint2*)Hq, (const float4*)ssrc,
                                          rec, off, csr, bias, (float*)d_out, N);
}

// Round 12
// 303.960 us; speedup vs baseline: 1.1614x; 1.1614x over previous
//
#include <hip/hip_runtime.h>

#define ALPHA 0.2f
#define EPS 1e-16f

static constexpr int F_IN = 256;
static constexpr int F_OUT = 128;
static constexpr int HEADS = 4;
static constexpr int COLS = HEADS * F_OUT; // 512

typedef __bf16 bf16x8 __attribute__((ext_vector_type(8)));
typedef float f32x4 __attribute__((ext_vector_type(4)));

static __device__ __forceinline__ unsigned short f2bf(float f) {
  unsigned int u = __float_as_uint(f);
  unsigned int r = (u + 0x7FFFu + ((u >> 16) & 1u)) >> 16;  // RN-even
  return (unsigned short)r;
}
static __device__ __forceinline__ float bf_lo(unsigned int u) {
  return __uint_as_float(u << 16);
}
static __device__ __forceinline__ float bf_hi(unsigned int u) {
  return __uint_as_float(u & 0xFFFF0000u);
}

static __device__ __forceinline__ void cvt8(const float4& p0, const float4& p1, bf16x8& v) {
  v[0] = (__bf16)p0.x; v[1] = (__bf16)p0.y; v[2] = (__bf16)p0.z; v[3] = (__bf16)p0.w;
  v[4] = (__bf16)p1.x; v[5] = (__bf16)p1.y; v[6] = (__bf16)p1.z; v[7] = (__bf16)p1.w;
}

// ---------------- K2: 128x128 MFMA GEMM (f32 in, cast-in-staging, LDS dbuf) ---
// Blocks 0..1023: edge-rank side pass (dispatched FIRST, overlaps gemm ramp).
// One barrier per K-step: read buf[cur] / write buf[cur^1].
// + fused score epilogue (block col == head bx) + int8(excess-128) quant.
// rec[n] (32B): bytes 0..15 = sdst (4 f32); bytes 16..31 = 8 bf16 scales.
// Hq row layout (per 64-col block b): u32 at byte 64b+4k holds cols {0,16,32,48}+k.
__global__ __launch_bounds__(256) void k_gemm_q(const float* __restrict__ A,
                                                const float* __restrict__ Wf,
                                                unsigned char* __restrict__ Hq,
                                                unsigned char* __restrict__ rec,
                                                float* __restrict__ ssrc,
                                                const float* __restrict__ Av, int N, int Tg,
                                                const int* __restrict__ src,
                                                int* __restrict__ cnt,
                                                unsigned short* __restrict__ rank, int E) {
  if ((int)blockIdx.x < 1024) {  // ---- rank side-blocks (first 1024) ----
    int i = (int)blockIdx.x * 256 + threadIdx.x;
    const int stride = 1024 * 256;
    for (; i < E; i += stride) rank[i] = (unsigned short)atomicAdd(&cnt[src[i]], 1);
    return;
  }
  __shared__ __bf16 As[2][128][40];
  __shared__ __bf16 Bs[2][128][40];
  __shared__ float sS[128], sD[128];
  const int gb = (int)blockIdx.x - 1024;
  // --- bijective XCD chunking over the Tg gemm blocks (col-fastest) ---
  const int q8 = Tg >> 3, r8 = Tg & 7;
  const int xcd = gb & 7, ii = gb >> 3;    // 1024 % 8 == 0 -> xcd mapping intact
  const int gp = (xcd < r8) ? xcd * (q8 + 1) + ii
                            : r8 * (q8 + 1) + (xcd - r8) * q8 + ii;
  const int by = gp >> 2;                  // row-tile
  const int bx = gp & 3;                   // 128-col block == head
  const int t = threadIdx.x;
  const int w = t >> 6, l = t & 63;
  const int wr = w >> 1, wc = w & 1;       // 2x2 wave grid, each 64x64
  const int m0 = by << 7, n0 = bx << 7;
  const int lr = t >> 1, seg16 = (t & 1) << 4;   // staging: row 0..127, col 0/16
  int ar = m0 + lr; if (ar >= N) ar = N - 1;     // clamp; stores guarded
  const float* Ap = A + (size_t)ar * F_IN + seg16;
  const float* Wp = Wf + (size_t)(n0 + lr) * F_IN + seg16;

  f32x4 acc[4][4] = {};
  // ---- prologue: stage step 0 into buffer 0 ----
  {
    const float4 f0 = *(const float4*)(Ap + 0);
    const float4 f1 = *(const float4*)(Ap + 4);
    const float4 f2 = *(const float4*)(Ap + 8);
    const float4 f3 = *(const float4*)(Ap + 12);
    const float4 g0 = *(const float4*)(Wp + 0);
    const float4 g1 = *(const float4*)(Wp + 4);
    const float4 g2 = *(const float4*)(Wp + 8);
    const float4 g3 = *(const float4*)(Wp + 12);
    bf16x8 v0, v1, u0, u1;
    cvt8(f0, f1, v0); cvt8(f2, f3, v1);
    cvt8(g0, g1, u0); cvt8(g2, g3, u1);
    *(bf16x8*)&As[0][lr][seg16] = v0;  *(bf16x8*)&As[0][lr][seg16 + 8] = v1;
    *(bf16x8*)&Bs[0][lr][seg16] = u0;  *(bf16x8*)&Bs[0][lr][seg16 + 8] = u1;
  }
  __syncthreads();
  const int kb = (l >> 4) << 3;
  const int arow_f = (wr << 6) + (l & 15);       // wave's A-frag base row
  const int brow_f = (wc << 6) + (l & 15);
#pragma unroll
  for (int s = 0; s < 8; ++s) {
    const int cur = s & 1;
    float4 f0, f1, f2, f3, g0, g1, g2, g3;
    if (s < 7) {                       // issue next-step loads BEFORE MFMA
      const int k0 = (s + 1) << 5;
      f0 = *(const float4*)(Ap + k0);      f1 = *(const float4*)(Ap + k0 + 4);
      f2 = *(const float4*)(Ap + k0 + 8);  f3 = *(const float4*)(Ap + k0 + 12);
      g0 = *(const float4*)(Wp + k0);      g1 = *(const float4*)(Wp + k0 + 4);
      g2 = *(const float4*)(Wp + k0 + 8);  g3 = *(const float4*)(Wp + k0 + 12);
    }
    bf16x8 af[4], bf_[4];
#pragma unroll
    for (int mi = 0; mi < 4; ++mi)
      af[mi] = *(const bf16x8*)&As[cur][arow_f + (mi << 4)][kb];
#pragma unroll
    for (int ni = 0; ni < 4; ++ni)
      bf_[ni] = *(const bf16x8*)&Bs[cur][brow_f + (ni << 4)][kb];
#pragma unroll
    for (int mi = 0; mi < 4; ++mi)
#pragma unroll
      for (int ni = 0; ni < 4; ++ni)
        acc[mi][ni] = __builtin_amdgcn_mfma_f32_16x16x32_bf16(af[mi], bf_[ni], acc[mi][ni], 0, 0, 0);
    if (s < 7) {                       // cvt + write NEXT buffer (after MFMA)
      bf16x8 v0, v1, u0, u1;
      cvt8(f0, f1, v0); cvt8(f2, f3, v1);
      cvt8(g0, g1, u0); cvt8(g2, g3, u1);
      *(bf16x8*)&As[cur ^ 1][lr][seg16] = v0;  *(bf16x8*)&As[cur ^ 1][lr][seg16 + 8] = v1;
      *(bf16x8*)&Bs[cur ^ 1][lr][seg16] = u0;  *(bf16x8*)&Bs[cur ^ 1][lr][seg16 + 8] = u1;
    }
    __syncthreads();                   // single barrier per step
  }
  // ---- score epilogue: s_src/s_dst for head bx from f32 accumulators ----
  {
    float as_[4], ad_[4];
#pragma unroll
    for (int ni = 0; ni < 4; ++ni) {
      const int f = (wc << 6) + (ni << 4) + (l & 15);
      as_[ni] = Av[bx * 256 + f];
      ad_[ni] = Av[bx * 256 + 128 + f];
    }
#pragma unroll
    for (int mi = 0; mi < 4; ++mi)
#pragma unroll
      for (int r = 0; r < 4; ++r) {
        float ds_ = 0.f, dd_ = 0.f;
#pragma unroll
        for (int ni = 0; ni < 4; ++ni) {
          ds_ = fmaf(acc[mi][ni][r], as_[ni], ds_);
          dd_ = fmaf(acc[mi][ni][r], ad_[ni], dd_);
        }
#pragma unroll
        for (int m = 1; m < 16; m <<= 1) {
          ds_ += __shfl_xor(ds_, m);
          dd_ += __shfl_xor(dd_, m);
        }
        if (wc == 0 && (l & 15) == 0) {
          const int rl = (wr << 6) + (mi << 4) + ((l >> 4) << 2) + r;
          sS[rl] = ds_; sD[rl] = dd_;
        }
      }
    __syncthreads();
    if (wc == 1) {
#pragma unroll
      for (int mi = 0; mi < 4; ++mi)
#pragma unroll
        for (int r = 0; r < 4; ++r) {
          float ds_ = 0.f, dd_ = 0.f;
#pragma unroll
          for (int ni = 0; ni < 4; ++ni) {
            ds_ = fmaf(acc[mi][ni][r], as_[ni], ds_);
            dd_ = fmaf(acc[mi][ni][r], ad_[ni], dd_);
          }
#pragma unroll
          for (int m = 1; m < 16; m <<= 1) {
            ds_ += __shfl_xor(ds_, m);
            dd_ += __shfl_xor(dd_, m);
          }
          if ((l & 15) == 0) {
            const int rl = (wr << 6) + (mi << 4) + ((l >> 4) << 2) + r;
            const int row = m0 + rl;
            if (row < N) {
              ssrc[row * 4 + bx] = sS[rl] + ds_;
              *(float*)&rec[(size_t)row * 32 + (bx << 2)] = sD[rl] + dd_;
            }
          }
        }
    }
  }
  // ---- quant epilogue: per-row absmax per 64-col block, excess-128 int8 ----
  const int bxg = (bx << 1) + wc;          // global 64-col block 0..7
#pragma unroll
  for (int mi = 0; mi < 4; ++mi)
#pragma unroll
    for (int r = 0; r < 4; ++r) {
      float mx = 0.f;
#pragma unroll
      for (int ni = 0; ni < 4; ++ni) mx = fmaxf(mx, fabsf(acc[mi][ni][r]));
#pragma unroll
      for (int m = 1; m < 16; m <<= 1) mx = fmaxf(mx, __shfl_xor(mx, m));
      const int row = m0 + (wr << 6) + (mi << 4) + ((l >> 4) << 2) + r;
      if (row < N) {
        const float inv = (mx > 0.f) ? 127.f / mx : 0.f;
        if ((l & 15) == 0)
          *(unsigned short*)&rec[(size_t)row * 32 + 16 + (bxg << 1)] = f2bf(mx * (1.f / 127.f));
        unsigned int pk = 0;
#pragma unroll
        for (int ni = 0; ni < 4; ++ni) {
          float tq = fminf(fmaxf(rintf(acc[mi][ni][r] * inv), -127.f), 127.f);
          pk |= ((unsigned int)(((int)tq + 128) & 255)) << (8 * ni);  // excess-128
        }
        *(unsigned int*)&Hq[(size_t)row * 512 + (bxg << 6) + ((l & 15) << 2)] = pk;
      }
    }
}

// ---------------- scans over cnt -> off ---------------------------------------
__global__ __launch_bounds__(1024) void k_scan1(int* __restrict__ cnt,
                                                int* __restrict__ bsum, int N) {
  __shared__ int ws[16];
  const int t = threadIdx.x, g = blockIdx.x * 1024 + t;
  const int lane = t & 63, w = t >> 6;
  int v = (g < N) ? cnt[g] : 0;
#pragma unroll
  for (int o = 1; o < 64; o <<= 1) {
    const int y = __shfl_up(v, o);
    if (lane >= o) v += y;
  }
  if (lane == 63) ws[w] = v;
  __syncthreads();
  if (w == 0) {
    int s = (lane < 16) ? ws[lane] : 0;
#pragma unroll
    for (int o = 1; o < 16; o <<= 1) {
      const int y = __shfl_up(s, o);
      if (lane >= o) s += y;
    }
    if (lane < 16) ws[lane] = s;
  }
  __syncthreads();
  v += (w > 0) ? ws[w - 1] : 0;
  if (g < N) cnt[g] = v;                  // in-place inclusive within chunk
  if (t == 1023) bsum[blockIdx.x] = v;
}

// fused: every block scans bsum locally (nb <= 256), then adds carry
__global__ __launch_bounds__(1024) void k_scan3(const int* __restrict__ part,
                                                const int* __restrict__ bsum,
                                                int* __restrict__ off, int N, int nb) {
  __shared__ int sbuf[256];
  const int t = threadIdx.x;
  if (t < 64) {
    int carry = 0;
    for (int base = 0; base < nb; base += 64) {
      int v = (base + t < nb) ? bsum[base + t] : 0;
#pragma unroll
      for (int o = 1; o < 64; o <<= 1) {
        const int y = __shfl_up(v, o);
        if (t >= o) v += y;
      }
      v += carry;
      if (base + t < nb) sbuf[base + t] = v;
      carry = __shfl(v, 63);
    }
  }
  __syncthreads();
  const int g = blockIdx.x * 1024 + t;
  if (g == 0) off[0] = 0;
  if (g < N) off[g + 1] = part[g] + (blockIdx.x ? sbuf[blockIdx.x - 1] : 0);
}

// ---------------- K3: scatter (no atomics; u16 dst) ---------------------------
__global__ void k_scatter(const int* __restrict__ src, const int* __restrict__ dst,
                          const int* __restrict__ off, const unsigned short* __restrict__ rank,
                          unsigned short* __restrict__ csr_dst, int E) {
  int i = blockIdx.x * blockDim.x + threadIdx.x;
  const int stride = gridDim.x * blockDim.x;
  for (; i < E; i += stride)
    csr_dst[off[src[i]] + rank[i]] = (unsigned short)dst[i];
}

// ---------------- K4: fused softmax + SpMM, excess-128 int8 -------------------
__global__ __launch_bounds__(256) void k_spmm(const uint2* __restrict__ Hq2,
    const float4* __restrict__ ssrc4, const unsigned char* __restrict__ rec,
    const int* __restrict__ off, const unsigned short* __restrict__ csr_dst,
    const float* __restrict__ bias, float* __restrict__ out, int N) {
  __shared__ float wbuf[4][8][72];   // [wave][col-block][edge], w[h]*scl[d][b]
  __shared__ int   ibuf[4][64];
  const int wv = threadIdx.x >> 6;
  const int lane = threadIdx.x & 63;
  const int n = (blockIdx.x << 2) + wv;
  if (n >= N) return;                 // wave-private LDS, no barriers
  const int hg = lane >> 4;           // head of this lane
  const int b8 = lane >> 3;           // 64-col block of this lane
  const float4 ss4 = ssrc4[n];
  float den4[4] = {};
  float acc[8] = {};
  float sw = 0.f;                     // sum of this lane's scaled weights
  const int beg = off[n], end = off[n + 1];
  for (int c0 = beg; c0 < end; c0 += 64) {
    const int cnt = min(64, end - c0);
    if (lane < cnt) {                 // -------- phase A --------
      const int d = csr_dst[c0 + lane];          // coalesced u16
      ibuf[wv][lane] = d << 6;                   // row base in uint2 units
      const float4 sd4 = *(const float4*)&rec[(size_t)d * 32];       // one line:
      const uint4  sc  = *(const uint4*)&rec[(size_t)d * 32 + 16];   // sdst+scales
      float e0 = ss4.x + sd4.x; e0 = fmaxf(e0, ALPHA * e0);
      float e1 = ss4.y + sd4.y; e1 = fmaxf(e1, ALPHA * e1);
      float e2 = ss4.z + sd4.z; e2 = fmaxf(e2, ALPHA * e2);
      float e3 = ss4.w + sd4.w; e3 = fmaxf(e3, ALPHA * e3);
      const float w0 = __expf(e0), w1 = __expf(e1), w2 = __expf(e2), w3 = __expf(e3);
      den4[0] += w0; den4[1] += w1; den4[2] += w2; den4[3] += w3;
      wbuf[wv][0][lane] = w0 * bf_lo(sc.x); wbuf[wv][1][lane] = w0 * bf_hi(sc.x);
      wbuf[wv][2][lane] = w1 * bf_lo(sc.y); wbuf[wv][3][lane] = w1 * bf_hi(sc.y);
      wbuf[wv][4][lane] = w2 * bf_lo(sc.z); wbuf[wv][5][lane] = w2 * bf_hi(sc.z);
      wbuf[wv][6][lane] = w3 * bf_lo(sc.w); wbuf[wv][7][lane] = w3 * bf_hi(sc.w);
    }
#pragma unroll 8
    for (int j = 0; j < cnt; ++j) {   // -------- phase B --------
      const float wgt = wbuf[wv][b8][j];         // LDS broadcast (scaled)
      const int db = ibuf[wv][j];                // LDS broadcast
      const uint2 q = Hq2[db + lane];            // 8B gather, 512B/row/wave
      sw += wgt;
      acc[0] = fmaf(wgt, (float)(q.x & 0xffu),         acc[0]);
      acc[1] = fmaf(wgt, (float)((q.x >> 8) & 0xffu),  acc[1]);
      acc[2] = fmaf(wgt, (float)((q.x >> 16) & 0xffu), acc[2]);
      acc[3] = fmaf(wgt, (float)(q.x >> 24),           acc[3]);
      acc[4] = fmaf(wgt, (float)(q.y & 0xffu),         acc[4]);
      acc[5] = fmaf(wgt, (float)((q.y >> 8) & 0xffu),  acc[5]);
      acc[6] = fmaf(wgt, (float)((q.y >> 16) & 0xffu), acc[6]);
      acc[7] = fmaf(wgt, (float)(q.y >> 24),           acc[7]);
    }
  }
#pragma unroll
  for (int k = 0; k < 4; ++k)
#pragma unroll
    for (int m = 1; m < 64; m <<= 1) den4[k] += __shfl_xor(den4[k], m);
  const float r = 1.f / (den4[hg] + EPS);
  const float corr = 128.f * sw;      // undo excess-128 bias
#pragma unroll
  for (int i = 0; i < 8; ++i) acc[i] = (acc[i] - corr) * r;
#pragma unroll
  for (int i = 0; i < 8; ++i) {       // sum the 4 heads (same feature at l^16,l^32)
    acc[i] += __shfl_xor(acc[i], 16);
    acc[i] += __shfl_xor(acc[i], 32);
  }
  if (lane < 16) {
    // permuted layout: acc[i] = feature 64*((lane>>3)&1) + (i&3)*16 + 2*(lane&7) + (i>>2)
    const int base = ((lane >> 3) & 1) * 64 + ((lane & 7) << 1);
#pragma unroll
    for (int k = 0; k < 4; ++k) {
      const float2 b2 = *(const float2*)&bias[base + k * 16];
      *(float2*)&out[(size_t)n * F_OUT + base + k * 16] =
          make_float2(0.25f * acc[k] + b2.x, 0.25f * acc[k + 4] + b2.y);
    }
  }
}

// ---------------- launch -------------------------------------------------------
extern "C" void kernel_launch(void* const* d_in, const int* in_sizes, int n_in,
                              void* d_out, int out_size, void* d_ws, size_t ws_size,
                              hipStream_t stream) {
  const float* H    = (const float*)d_in[0];
  const int*   ei   = (const int*)d_in[1];
  const float* W    = (const float*)d_in[2];   // [4,128,256] == [512,256]
  const float* a    = (const float*)d_in[3];   // [4,256]
  const float* bias = (const float*)d_in[4];   // [128]
  const int N = in_sizes[0] / F_IN;
  const int E = in_sizes[1] / 2;
  const int* src = ei;
  const int* dst = ei + E;

  char* ws = (char*)d_ws;
  size_t o = 0;
  auto alloc = [&](size_t bytes) -> void* {
    void* p = ws + o;
    o = (o + bytes + 255) & ~(size_t)255;
    return p;
  };
  unsigned char*  Hq  = (unsigned char*)alloc((size_t)N * COLS);        // 25.6 MB int8
  float* ssrc = (float*)alloc((size_t)N * HEADS * sizeof(float));
  unsigned char* rec = (unsigned char*)alloc((size_t)N * 32);           // 1.6 MB packed
  int*   cnt  = (int*)alloc((size_t)N * sizeof(int));
  int*   off  = (int*)alloc(((size_t)N + 1) * sizeof(int));
  unsigned short* csr = (unsigned short*)alloc((size_t)E * sizeof(unsigned short));
  unsigned short* rank = (unsigned short*)alloc((size_t)E * sizeof(unsigned short));
  const int nb = (N + 1023) / 1024;
  int*   bsum = (int*)alloc((size_t)nb * sizeof(int));

  hipMemsetAsync(cnt, 0, (size_t)N * sizeof(int), stream);

  const int nb128 = (N + 127) / 128;
  const int Tg = 4 * nb128;
  k_gemm_q<<<1024 + Tg, 256, 0, stream>>>(H, W, Hq, rec, ssrc, a, N, Tg,
                                          src, cnt, rank, E);
  k_scan1<<<nb, 1024, 0, stream>>>(cnt, bsum, N);
  k_scan3<<<nb, 1024, 0, stream>>>(cnt, bsum, off, N, nb);
  k_scatter<<<1024, 256, 0, stream>>>(src, dst, off, rank, csr, E);
  k_spmm<<<(N + 3) / 4, 256, 0, stream>>>((const uint2*)Hq, (const float4*)ssrc,
                                          rec, off, csr, bias, (float*)d_out, N);
}

// Round 13
// 303.852 us; speedup vs baseline: 1.1618x; 1.0004x over previous
//
#include <hip/hip_runtime.h>

#define ALPHA 0.2f
#define EPS 1e-16f

static constexpr int F_IN = 256;
static constexpr int F_OUT = 128;
static constexpr int HEADS = 4;
static constexpr int COLS = HEADS * F_OUT; // 512
static constexpr int NB_SORT = 256;        // blocks in the LDS counting sort

typedef __bf16 bf16x8 __attribute__((ext_vector_type(8)));
typedef float f32x4 __attribute__((ext_vector_type(4)));

static __device__ __forceinline__ unsigned short f2bf(float f) {
  unsigned int u = __float_as_uint(f);
  unsigned int r = (u + 0x7FFFu + ((u >> 16) & 1u)) >> 16;  // RN-even
  return (unsigned short)r;
}
static __device__ __forceinline__ float bf_lo(unsigned int u) {
  return __uint_as_float(u << 16);
}
static __device__ __forceinline__ float bf_hi(unsigned int u) {
  return __uint_as_float(u & 0xFFFF0000u);
}
static __device__ __forceinline__ void cvt8(const float4& p0, const float4& p1, bf16x8& v) {
  v[0] = (__bf16)p0.x; v[1] = (__bf16)p0.y; v[2] = (__bf16)p0.z; v[3] = (__bf16)p0.w;
  v[4] = (__bf16)p1.x; v[5] = (__bf16)p1.y; v[6] = (__bf16)p1.z; v[7] = (__bf16)p1.w;
}

// ---------------- CSR build, atomic-free (LDS-privatized counting sort) -------
// bins: two u16 counts packed per u32 (src s -> word s>>1, half s&1).
// N <= 50176 assumed (problem: N = 50000).

__global__ __launch_bounds__(256) void k_cnt(const int* __restrict__ src,
                                             unsigned short* __restrict__ bcnt,
                                             int N, int E) {
  __shared__ unsigned int bins[25088];
  const int b = blockIdx.x, t = threadIdx.x;
  const int NBIN = (N + 1) >> 1;
  for (int j = t; j < NBIN; j += 256) bins[j] = 0u;
  __syncthreads();
  const int CE = (E + NB_SORT - 1) / NB_SORT;
  const int i1 = min(E, (b + 1) * CE);
  for (int i = b * CE + t; i < i1; i += 256) {
    const int s = src[i];
    atomicAdd(&bins[s >> 1], 1u << ((s & 1) << 4));   // LDS atomic
  }
  __syncthreads();
  unsigned short* row = bcnt + (size_t)b * N;
  for (int s = t; s < N; s += 256)
    row[s] = (unsigned short)((bins[s >> 1] >> ((s & 1) << 4)) & 0xffffu);
}

__global__ __launch_bounds__(1024) void k_colsum(const unsigned short* __restrict__ bcnt,
                                                 int* __restrict__ cnt, int N) {
  const int s = blockIdx.x * 1024 + threadIdx.x;
  if (s >= N) return;
  int run = 0;
  for (int b = 0; b < NB_SORT; ++b) run += bcnt[(size_t)b * N + s];  // coalesced
  cnt[s] = run;
}

__global__ __launch_bounds__(1024) void k_base(const unsigned short* __restrict__ bcnt,
                                               unsigned short* __restrict__ base_rel, int N) {
  const int s = blockIdx.x * 1024 + threadIdx.x;
  if (s >= N) return;
  int run = 0;
  for (int b = 0; b < NB_SORT; ++b) {
    const size_t idx = (size_t)b * N + s;
    const int v = bcnt[idx];
    base_rel[idx] = (unsigned short)run;   // prefix excl., fits u16 (max degree ~70)
    run += v;
  }
}

__global__ __launch_bounds__(256) void k_place(const int* __restrict__ src,
                                               const int* __restrict__ dst,
                                               const int* __restrict__ off,
                                               const unsigned short* __restrict__ base_rel,
                                               unsigned short* __restrict__ csr,
                                               int N, int E) {
  __shared__ unsigned int bins[25088];
  const int b = blockIdx.x, t = threadIdx.x;
  const int NBIN = (N + 1) >> 1;
  for (int j = t; j < NBIN; j += 256) bins[j] = 0u;
  __syncthreads();
  const unsigned short* brow = base_rel + (size_t)b * N;
  const int CE = (E + NB_SORT - 1) / NB_SORT;
  const int i1 = min(E, (b + 1) * CE);
  for (int i = b * CE + t; i < i1; i += 256) {
    const int s = src[i];
    const unsigned int old = atomicAdd(&bins[s >> 1], 1u << ((s & 1) << 4));
    const int local = (old >> ((s & 1) << 4)) & 0xffff;
    csr[off[s] + brow[s] + local] = (unsigned short)dst[i];
  }
}

// ---------------- K2: 128x128 MFMA GEMM (f32 in, cast-in-staging, r9 best) ----
// + fused score epilogue (block col == head bx) + int8(excess-128) quant.
// rec[n] (32B): bytes 0..15 = sdst (4 f32); bytes 16..31 = 8 bf16 scales.
// Hq row layout (per 64-col block b): u32 at byte 64b+4k holds cols {0,16,32,48}+k.
__global__ __launch_bounds__(256) void k_gemm_q(const float* __restrict__ A,
                                                const float* __restrict__ Wf,
                                                unsigned char* __restrict__ Hq,
                                                unsigned char* __restrict__ rec,
                                                float* __restrict__ ssrc,
                                                const float* __restrict__ Av, int N, int Tg) {
  __shared__ __bf16 As[128][40];
  __shared__ __bf16 Bs[128][40];
  __shared__ float sS[128], sD[128];
  // --- bijective XCD chunking over the Tg gemm blocks (col-fastest) ---
  const int q8 = Tg >> 3, r8 = Tg & 7;
  const int xcd = blockIdx.x & 7, ii = blockIdx.x >> 3;
  const int gp = (xcd < r8) ? xcd * (q8 + 1) + ii
                            : r8 * (q8 + 1) + (xcd - r8) * q8 + ii;
  const int by = gp >> 2;                  // row-tile
  const int bx = gp & 3;                   // 128-col block == head
  const int t = threadIdx.x;
  const int w = t >> 6, l = t & 63;
  const int wr = w >> 1, wc = w & 1;       // 2x2 wave grid, each 64x64
  const int m0 = by << 7, n0 = bx << 7;
  const int lr = t >> 1, seg16 = (t & 1) << 4;   // staging: row 0..127, col 0/16
  int ar = m0 + lr; if (ar >= N) ar = N - 1;     // clamp; stores guarded
  const float* Ap = A + (size_t)ar * F_IN + seg16;
  const float* Wp = Wf + (size_t)(n0 + lr) * F_IN + seg16;
  f32x4 acc[4][4] = {};
  for (int k0 = 0; k0 < F_IN; k0 += 32) {
    const float4 f0 = *(const float4*)(Ap + k0);
    const float4 f1 = *(const float4*)(Ap + k0 + 4);
    const float4 f2 = *(const float4*)(Ap + k0 + 8);
    const float4 f3 = *(const float4*)(Ap + k0 + 12);
    const float4 g0 = *(const float4*)(Wp + k0);
    const float4 g1 = *(const float4*)(Wp + k0 + 4);
    const float4 g2 = *(const float4*)(Wp + k0 + 8);
    const float4 g3 = *(const float4*)(Wp + k0 + 12);
    bf16x8 v0, v1, u0, u1;
    cvt8(f0, f1, v0); cvt8(f2, f3, v1);
    cvt8(g0, g1, u0); cvt8(g2, g3, u1);
    __syncthreads();
    *(bf16x8*)&As[lr][seg16] = v0;  *(bf16x8*)&As[lr][seg16 + 8] = v1;
    *(bf16x8*)&Bs[lr][seg16] = u0;  *(bf16x8*)&Bs[lr][seg16 + 8] = u1;
    __syncthreads();
    const int kb = (l >> 4) << 3;
    bf16x8 af[4], bf_[4];
#pragma unroll
    for (int mi = 0; mi < 4; ++mi)
      af[mi] = *(const bf16x8*)&As[(wr << 6) + (mi << 4) + (l & 15)][kb];
#pragma unroll
    for (int ni = 0; ni < 4; ++ni)
      bf_[ni] = *(const bf16x8*)&Bs[(wc << 6) + (ni << 4) + (l & 15)][kb];
#pragma unroll
    for (int mi = 0; mi < 4; ++mi)
#pragma unroll
      for (int ni = 0; ni < 4; ++ni)
        acc[mi][ni] = __builtin_amdgcn_mfma_f32_16x16x32_bf16(af[mi], bf_[ni], acc[mi][ni], 0, 0, 0);
  }
  // ---- score epilogue: s_src/s_dst for head bx from f32 accumulators ----
  {
    float as_[4], ad_[4];
#pragma unroll
    for (int ni = 0; ni < 4; ++ni) {
      const int f = (wc << 6) + (ni << 4) + (l & 15);
      as_[ni] = Av[bx * 256 + f];
      ad_[ni] = Av[bx * 256 + 128 + f];
    }
#pragma unroll
    for (int mi = 0; mi < 4; ++mi)
#pragma unroll
      for (int r = 0; r < 4; ++r) {
        float ds_ = 0.f, dd_ = 0.f;
#pragma unroll
        for (int ni = 0; ni < 4; ++ni) {
          ds_ = fmaf(acc[mi][ni][r], as_[ni], ds_);
          dd_ = fmaf(acc[mi][ni][r], ad_[ni], dd_);
        }
#pragma unroll
        for (int m = 1; m < 16; m <<= 1) {
          ds_ += __shfl_xor(ds_, m);
          dd_ += __shfl_xor(dd_, m);
        }
        if (wc == 0 && (l & 15) == 0) {
          const int rl = (wr << 6) + (mi << 4) + ((l >> 4) << 2) + r;
          sS[rl] = ds_; sD[rl] = dd_;
        }
      }
    __syncthreads();
    if (wc == 1) {
#pragma unroll
      for (int mi = 0; mi < 4; ++mi)
#pragma unroll
        for (int r = 0; r < 4; ++r) {
          float ds_ = 0.f, dd_ = 0.f;
#pragma unroll
          for (int ni = 0; ni < 4; ++ni) {
            ds_ = fmaf(acc[mi][ni][r], as_[ni], ds_);
            dd_ = fmaf(acc[mi][ni][r], ad_[ni], dd_);
          }
#pragma unroll
          for (int m = 1; m < 16; m <<= 1) {
            ds_ += __shfl_xor(ds_, m);
            dd_ += __shfl_xor(dd_, m);
          }
          if ((l & 15) == 0) {
            const int rl = (wr << 6) + (mi << 4) + ((l >> 4) << 2) + r;
            const int row = m0 + rl;
            if (row < N) {
              ssrc[row * 4 + bx] = sS[rl] + ds_;
              *(float*)&rec[(size_t)row * 32 + (bx << 2)] = sD[rl] + dd_;
            }
          }
        }
    }
  }
  // ---- quant epilogue: per-row absmax per 64-col block, excess-128 int8 ----
  const int bxg = (bx << 1) + wc;          // global 64-col block 0..7
#pragma unroll
  for (int mi = 0; mi < 4; ++mi)
#pragma unroll
    for (int r = 0; r < 4; ++r) {
      float mx = 0.f;
#pragma unroll
      for (int ni = 0; ni < 4; ++ni) mx = fmaxf(mx, fabsf(acc[mi][ni][r]));
#pragma unroll
      for (int m = 1; m < 16; m <<= 1) mx = fmaxf(mx, __shfl_xor(mx, m));
      const int row = m0 + (wr << 6) + (mi << 4) + ((l >> 4) << 2) + r;
      if (row < N) {
        const float inv = (mx > 0.f) ? 127.f / mx : 0.f;
        if ((l & 15) == 0)
          *(unsigned short*)&rec[(size_t)row * 32 + 16 + (bxg << 1)] = f2bf(mx * (1.f / 127.f));
        unsigned int pk = 0;
#pragma unroll
        for (int ni = 0; ni < 4; ++ni) {
          float tq = fminf(fmaxf(rintf(acc[mi][ni][r] * inv), -127.f), 127.f);
          pk |= ((unsigned int)(((int)tq + 128) & 255)) << (8 * ni);  // excess-128
        }
        *(unsigned int*)&Hq[(size_t)row * 512 + (bxg << 6) + ((l & 15) << 2)] = pk;
      }
    }
}

// ---------------- scans over cnt -> off ---------------------------------------
__global__ __launch_bounds__(1024) void k_scan1(int* __restrict__ cnt,
                                                int* __restrict__ bsum, int N) {
  __shared__ int ws[16];
  const int t = threadIdx.x, g = blockIdx.x * 1024 + t;
  const int lane = t & 63, w = t >> 6;
  int v = (g < N) ? cnt[g] : 0;
#pragma unroll
  for (int o = 1; o < 64; o <<= 1) {
    const int y = __shfl_up(v, o);
    if (lane >= o) v += y;
  }
  if (lane == 63) ws[w] = v;
  __syncthreads();
  if (w == 0) {
    int s = (lane < 16) ? ws[lane] : 0;
#pragma unroll
    for (int o = 1; o < 16; o <<= 1) {
      const int y = __shfl_up(s, o);
      if (lane >= o) s += y;
    }
    if (lane < 16) ws[lane] = s;
  }
  __syncthreads();
  v += (w > 0) ? ws[w - 1] : 0;
  if (g < N) cnt[g] = v;                  // in-place inclusive within chunk
  if (t == 1023) bsum[blockIdx.x] = v;
}

// fused: every block scans bsum locally (nb <= 256), then adds carry
__global__ __launch_bounds__(1024) void k_scan3(const int* __restrict__ part,
                                                const int* __restrict__ bsum,
                                                int* __restrict__ off, int N, int nb) {
  __shared__ int sbuf[256];
  const int t = threadIdx.x;
  if (t < 64) {
    int carry = 0;
    for (int base = 0; base < nb; base += 64) {
      int v = (base + t < nb) ? bsum[base + t] : 0;
#pragma unroll
      for (int o = 1; o < 64; o <<= 1) {
        const int y = __shfl_up(v, o);
        if (t >= o) v += y;
      }
      v += carry;
      if (base + t < nb) sbuf[base + t] = v;
      carry = __shfl(v, 63);
    }
  }
  __syncthreads();
  const int g = blockIdx.x * 1024 + t;
  if (g == 0) off[0] = 0;
  if (g < N) off[g + 1] = part[g] + (blockIdx.x ? sbuf[blockIdx.x - 1] : 0);
}

// ---------------- K4: fused softmax + SpMM, excess-128 int8 -------------------
__global__ __launch_bounds__(256) void k_spmm(const uint2* __restrict__ Hq2,
    const float4* __restrict__ ssrc4, const unsigned char* __restrict__ rec,
    const int* __restrict__ off, const unsigned short* __restrict__ csr_dst,
    const float* __restrict__ bias, float* __restrict__ out, int N) {
  __shared__ float wbuf[4][8][72];   // [wave][col-block][edge], w[h]*scl[d][b]
  __shared__ int   ibuf[4][64];
  const int wv = threadIdx.x >> 6;
  const int lane = threadIdx.x & 63;
  const int n = (blockIdx.x << 2) + wv;
  if (n >= N) return;                 // wave-private LDS, no barriers
  const int hg = lane >> 4;           // head of this lane
  const int b8 = lane >> 3;           // 64-col block of this lane
  const float4 ss4 = ssrc4[n];
  float den4[4] = {};
  float acc[8] = {};
  float sw = 0.f;                     // sum of this lane's scaled weights
  const int beg = off[n], end = off[n + 1];
  for (int c0 = beg; c0 < end; c0 += 64) {
    const int cnt = min(64, end - c0);
    if (lane < cnt) {                 // -------- phase A --------
      const int d = csr_dst[c0 + lane];          // coalesced u16
      ibuf[wv][lane] = d << 6;                   // row base in uint2 units
      const float4 sd4 = *(const float4*)&rec[(size_t)d * 32];       // one line:
      const uint4  sc  = *(const uint4*)&rec[(size_t)d * 32 + 16];   // sdst+scales
      float e0 = ss4.x + sd4.x; e0 = fmaxf(e0, ALPHA * e0);
      float e1 = ss4.y + sd4.y; e1 = fmaxf(e1, ALPHA * e1);
      float e2 = ss4.z + sd4.z; e2 = fmaxf(e2, ALPHA * e2);
      float e3 = ss4.w + sd4.w; e3 = fmaxf(e3, ALPHA * e3);
      const float w0 = __expf(e0), w1 = __expf(e1), w2 = __expf(e2), w3 = __expf(e3);
      den4[0] += w0; den4[1] += w1; den4[2] += w2; den4[3] += w3;
      wbuf[wv][0][lane] = w0 * bf_lo(sc.x); wbuf[wv][1][lane] = w0 * bf_hi(sc.x);
      wbuf[wv][2][lane] = w1 * bf_lo(sc.y); wbuf[wv][3][lane] = w1 * bf_hi(sc.y);
      wbuf[wv][4][lane] = w2 * bf_lo(sc.z); wbuf[wv][5][lane] = w2 * bf_hi(sc.z);
      wbuf[wv][6][lane] = w3 * bf_lo(sc.w); wbuf[wv][7][lane] = w3 * bf_hi(sc.w);
    }
#pragma unroll 8
    for (int j = 0; j < cnt; ++j) {   // -------- phase B --------
      const float wgt = wbuf[wv][b8][j];         // LDS broadcast (scaled)
      const int db = ibuf[wv][j];                // LDS broadcast
      const uint2 q = Hq2[db + lane];            // 8B gather, 512B/row/wave
      sw += wgt;
      acc[0] = fmaf(wgt, (float)(q.x & 0xffu),         acc[0]);
      acc[1] = fmaf(wgt, (float)((q.x >> 8) & 0xffu),  acc[1]);
      acc[2] = fmaf(wgt, (float)((q.x >> 16) & 0xffu), acc[2]);
      acc[3] = fmaf(wgt, (float)(q.x >> 24),           acc[3]);
      acc[4] = fmaf(wgt, (float)(q.y & 0xffu),         acc[4]);
      acc[5] = fmaf(wgt, (float)((q.y >> 8) & 0xffu),  acc[5]);
      acc[6] = fmaf(wgt, (float)((q.y >> 16) & 0xffu), acc[6]);
      acc[7] = fmaf(wgt, (float)(q.y >> 24),           acc[7]);
    }
  }
#pragma unroll
  for (int k = 0; k < 4; ++k)
#pragma unroll
    for (int m = 1; m < 64; m <<= 1) den4[k] += __shfl_xor(den4[k], m);
  const float r = 1.f / (den4[hg] + EPS);
  const float corr = 128.f * sw;      // undo excess-128 bias
#pragma unroll
  for (int i = 0; i < 8; ++i) acc[i] = (acc[i] - corr) * r;
#pragma unroll
  for (int i = 0; i < 8; ++i) {       // sum the 4 heads (same feature at l^16,l^32)
    acc[i] += __shfl_xor(acc[i], 16);
    acc[i] += __shfl_xor(acc[i], 32);
  }
  if (lane < 16) {
    // permuted layout: acc[i] = feature 64*((lane>>3)&1) + (i&3)*16 + 2*(lane&7) + (i>>2)
    const int base = ((lane >> 3) & 1) * 64 + ((lane & 7) << 1);
#pragma unroll
    for (int k = 0; k < 4; ++k) {
      const float2 b2 = *(const float2*)&bias[base + k * 16];
      *(float2*)&out[(size_t)n * F_OUT + base + k * 16] =
          make_float2(0.25f * acc[k] + b2.x, 0.25f * acc[k + 4] + b2.y);
    }
  }
}

// ---------------- launch -------------------------------------------------------
extern "C" void kernel_launch(void* const* d_in, const int* in_sizes, int n_in,
                              void* d_out, int out_size, void* d_ws, size_t ws_size,
                              hipStream_t stream) {
  const float* H    = (const float*)d_in[0];
  const int*   ei   = (const int*)d_in[1];
  const float* W    = (const float*)d_in[2];   // [4,128,256] == [512,256]
  const float* a    = (const float*)d_in[3];   // [4,256]
  const float* bias = (const float*)d_in[4];   // [128]
  const int N = in_sizes[0] / F_IN;
  const int E = in_sizes[1] / 2;
  const int* src = ei;
  const int* dst = ei + E;

  char* ws = (char*)d_ws;
  size_t o = 0;
  auto alloc = [&](size_t bytes) -> void* {
    void* p = ws + o;
    o = (o + bytes + 255) & ~(size_t)255;
    return p;
  };
  unsigned char*  Hq  = (unsigned char*)alloc((size_t)N * COLS);        // 25.6 MB int8
  float* ssrc = (float*)alloc((size_t)N * HEADS * sizeof(float));
  unsigned char* rec = (unsigned char*)alloc((size_t)N * 32);           // 1.6 MB packed
  int*   cnt  = (int*)alloc((size_t)N * sizeof(int));
  int*   off  = (int*)alloc(((size_t)N + 1) * sizeof(int));
  unsigned short* csr  = (unsigned short*)alloc((size_t)E * sizeof(unsigned short));
  unsigned short* bcnt = (unsigned short*)alloc((size_t)NB_SORT * N * sizeof(unsigned short)); // 25.6 MB
  unsigned short* base = (unsigned short*)alloc((size_t)NB_SORT * N * sizeof(unsigned short)); // 25.6 MB
  const int nb = (N + 1023) / 1024;
  int*   bsum = (int*)alloc((size_t)nb * sizeof(int));

  const int nb128 = (N + 127) / 128;
  const int Tg = 4 * nb128;

  k_cnt<<<NB_SORT, 256, 0, stream>>>(src, bcnt, N, E);                 // no global atomics
  k_gemm_q<<<Tg, 256, 0, stream>>>(H, W, Hq, rec, ssrc, a, N, Tg);
  k_colsum<<<nb, 1024, 0, stream>>>(bcnt, cnt, N);
  k_scan1<<<nb, 1024, 0, stream>>>(cnt, bsum, N);
  k_scan3<<<nb, 1024, 0, stream>>>(cnt, bsum, off, N, nb);
  k_base<<<nb, 1024, 0, stream>>>(bcnt, base, N);
  k_place<<<NB_SORT, 256, 0, stream>>>(src, dst, off, base, csr, N, E); // no global atomics
  k_spmm<<<(N + 3) / 4, 256, 0, stream>>>((const uint2*)Hq, (const float4*)ssrc,
                                          rec, off, csr, bias, (float*)d_out, N);
}

// Round 14
// 290.112 us; speedup vs baseline: 1.2168x; 1.0474x over previous
//
#include <hip/hip_runtime.h>

#define ALPHA 0.2f
#define EPS 1e-16f

static constexpr int F_IN = 256;
static constexpr int F_OUT = 128;
static constexpr int HEADS = 4;
static constexpr int COLS = HEADS * F_OUT; // 512

typedef __bf16 bf16x8 __attribute__((ext_vector_type(8)));
typedef float f32x4 __attribute__((ext_vector_type(4)));

static __device__ __forceinline__ unsigned short f2bf(float f) {
  unsigned int u = __float_as_uint(f);
  unsigned int r = (u + 0x7FFFu + ((u >> 16) & 1u)) >> 16;  // RN-even
  return (unsigned short)r;
}
static __device__ __forceinline__ float bf_lo(unsigned int u) {
  return __uint_as_float(u << 16);
}
static __device__ __forceinline__ float bf_hi(unsigned int u) {
  return __uint_as_float(u & 0xFFFF0000u);
}
static __device__ __forceinline__ void cvt8(const float4& p0, const float4& p1, bf16x8& v) {
  v[0] = (__bf16)p0.x; v[1] = (__bf16)p0.y; v[2] = (__bf16)p0.z; v[3] = (__bf16)p0.w;
  v[4] = (__bf16)p1.x; v[5] = (__bf16)p1.y; v[6] = (__bf16)p1.z; v[7] = (__bf16)p1.w;
}

// ---------------- K2: 128x128 MFMA GEMM (f32 in, cast-in-staging) -------------
// Blocks 0..Tg-1: gemm (dispatched FIRST — the long pole starts immediately).
// Blocks Tg..Tg+1023: edge-rank side pass (fills gemm's stall cycles / tail).
// + fused score epilogue (block col == head bx) + int8(excess-128) quant.
// rec[n] (32B): bytes 0..15 = sdst (4 f32); bytes 16..31 = 8 bf16 scales.
// Hq row layout (per 64-col block b): u32 at byte 64b+4k holds cols {0,16,32,48}+k.
__global__ __launch_bounds__(256) void k_gemm_q(const float* __restrict__ A,
                                                const float* __restrict__ Wf,
                                                unsigned char* __restrict__ Hq,
                                                unsigned char* __restrict__ rec,
                                                float* __restrict__ ssrc,
                                                const float* __restrict__ Av, int N, int Tg,
                                                const int* __restrict__ src,
                                                int* __restrict__ cnt,
                                                unsigned short* __restrict__ rank, int E) {
  if ((int)blockIdx.x >= Tg) {   // ---- rank side-blocks (last 1024) ----
    int i = ((int)blockIdx.x - Tg) * 256 + threadIdx.x;
    const int stride = 1024 * 256;
    for (; i < E; i += stride) rank[i] = (unsigned short)atomicAdd(&cnt[src[i]], 1);
    return;
  }
  __shared__ __bf16 As[128][40];
  __shared__ __bf16 Bs[128][40];
  __shared__ float sS[128], sD[128];
  // --- bijective XCD chunking over the Tg gemm blocks (col-fastest) ---
  const int q8 = Tg >> 3, r8 = Tg & 7;
  const int xcd = blockIdx.x & 7, ii = blockIdx.x >> 3;
  const int gp = (xcd < r8) ? xcd * (q8 + 1) + ii
                            : r8 * (q8 + 1) + (xcd - r8) * q8 + ii;
  const int by = gp >> 2;                  // row-tile
  const int bx = gp & 3;                   // 128-col block == head
  const int t = threadIdx.x;
  const int w = t >> 6, l = t & 63;
  const int wr = w >> 1, wc = w & 1;       // 2x2 wave grid, each 64x64
  const int m0 = by << 7, n0 = bx << 7;
  const int lr = t >> 1, seg16 = (t & 1) << 4;   // staging: row 0..127, col 0/16
  int ar = m0 + lr; if (ar >= N) ar = N - 1;     // clamp; stores guarded
  const float* Ap = A + (size_t)ar * F_IN + seg16;
  const float* Wp = Wf + (size_t)(n0 + lr) * F_IN + seg16;
  f32x4 acc[4][4] = {};
  for (int k0 = 0; k0 < F_IN; k0 += 32) {
    const float4 f0 = *(const float4*)(Ap + k0);
    const float4 f1 = *(const float4*)(Ap + k0 + 4);
    const float4 f2 = *(const float4*)(Ap + k0 + 8);
    const float4 f3 = *(const float4*)(Ap + k0 + 12);
    const float4 g0 = *(const float4*)(Wp + k0);
    const float4 g1 = *(const float4*)(Wp + k0 + 4);
    const float4 g2 = *(const float4*)(Wp + k0 + 8);
    const float4 g3 = *(const float4*)(Wp + k0 + 12);
    bf16x8 v0, v1, u0, u1;
    cvt8(f0, f1, v0); cvt8(f2, f3, v1);
    cvt8(g0, g1, u0); cvt8(g2, g3, u1);
    __syncthreads();
    *(bf16x8*)&As[lr][seg16] = v0;  *(bf16x8*)&As[lr][seg16 + 8] = v1;
    *(bf16x8*)&Bs[lr][seg16] = u0;  *(bf16x8*)&Bs[lr][seg16 + 8] = u1;
    __syncthreads();
    const int kb = (l >> 4) << 3;
    bf16x8 af[4], bf_[4];
#pragma unroll
    for (int mi = 0; mi < 4; ++mi)
      af[mi] = *(const bf16x8*)&As[(wr << 6) + (mi << 4) + (l & 15)][kb];
#pragma unroll
    for (int ni = 0; ni < 4; ++ni)
      bf_[ni] = *(const bf16x8*)&Bs[(wc << 6) + (ni << 4) + (l & 15)][kb];
#pragma unroll
    for (int mi = 0; mi < 4; ++mi)
#pragma unroll
      for (int ni = 0; ni < 4; ++ni)
        acc[mi][ni] = __builtin_amdgcn_mfma_f32_16x16x32_bf16(af[mi], bf_[ni], acc[mi][ni], 0, 0, 0);
  }
  // ---- score epilogue: s_src/s_dst for head bx from f32 accumulators ----
  {
    float as_[4], ad_[4];
#pragma unroll
    for (int ni = 0; ni < 4; ++ni) {
      const int f = (wc << 6) + (ni << 4) + (l & 15);
      as_[ni] = Av[bx * 256 + f];
      ad_[ni] = Av[bx * 256 + 128 + f];
    }
#pragma unroll
    for (int mi = 0; mi < 4; ++mi)
#pragma unroll
      for (int r = 0; r < 4; ++r) {
        float ds_ = 0.f, dd_ = 0.f;
#pragma unroll
        for (int ni = 0; ni < 4; ++ni) {
          ds_ = fmaf(acc[mi][ni][r], as_[ni], ds_);
          dd_ = fmaf(acc[mi][ni][r], ad_[ni], dd_);
        }
#pragma unroll
        for (int m = 1; m < 16; m <<= 1) {
          ds_ += __shfl_xor(ds_, m);
          dd_ += __shfl_xor(dd_, m);
        }
        if (wc == 0 && (l & 15) == 0) {
          const int rl = (wr << 6) + (mi << 4) + ((l >> 4) << 2) + r;
          sS[rl] = ds_; sD[rl] = dd_;
        }
      }
    __syncthreads();
    if (wc == 1) {
#pragma unroll
      for (int mi = 0; mi < 4; ++mi)
#pragma unroll
        for (int r = 0; r < 4; ++r) {
          float ds_ = 0.f, dd_ = 0.f;
#pragma unroll
          for (int ni = 0; ni < 4; ++ni) {
            ds_ = fmaf(acc[mi][ni][r], as_[ni], ds_);
            dd_ = fmaf(acc[mi][ni][r], ad_[ni], dd_);
          }
#pragma unroll
          for (int m = 1; m < 16; m <<= 1) {
            ds_ += __shfl_xor(ds_, m);
            dd_ += __shfl_xor(dd_, m);
          }
          if ((l & 15) == 0) {
            const int rl = (wr << 6) + (mi << 4) + ((l >> 4) << 2) + r;
            const int row = m0 + rl;
            if (row < N) {
              ssrc[row * 4 + bx] = sS[rl] + ds_;
              *(float*)&rec[(size_t)row * 32 + (bx << 2)] = sD[rl] + dd_;
            }
          }
        }
    }
  }
  // ---- quant epilogue: per-row absmax per 64-col block, excess-128 int8 ----
  const int bxg = (bx << 1) + wc;          // global 64-col block 0..7
#pragma unroll
  for (int mi = 0; mi < 4; ++mi)
#pragma unroll
    for (int r = 0; r < 4; ++r) {
      float mx = 0.f;
#pragma unroll
      for (int ni = 0; ni < 4; ++ni) mx = fmaxf(mx, fabsf(acc[mi][ni][r]));
#pragma unroll
      for (int m = 1; m < 16; m <<= 1) mx = fmaxf(mx, __shfl_xor(mx, m));
      const int row = m0 + (wr << 6) + (mi << 4) + ((l >> 4) << 2) + r;
      if (row < N) {
        const float inv = (mx > 0.f) ? 127.f / mx : 0.f;
        if ((l & 15) == 0)
          *(unsigned short*)&rec[(size_t)row * 32 + 16 + (bxg << 1)] = f2bf(mx * (1.f / 127.f));
        unsigned int pk = 0;
#pragma unroll
        for (int ni = 0; ni < 4; ++ni) {
          float tq = fminf(fmaxf(rintf(acc[mi][ni][r] * inv), -127.f), 127.f);
          pk |= ((unsigned int)(((int)tq + 128) & 255)) << (8 * ni);  // excess-128
        }
        *(unsigned int*)&Hq[(size_t)row * 512 + (bxg << 6) + ((l & 15) << 2)] = pk;
      }
    }
}

// ---------------- scans over cnt -> off ---------------------------------------
__global__ __launch_bounds__(1024) void k_scan1(int* __restrict__ cnt,
                                                int* __restrict__ bsum, int N) {
  __shared__ int ws[16];
  const int t = threadIdx.x, g = blockIdx.x * 1024 + t;
  const int lane = t & 63, w = t >> 6;
  int v = (g < N) ? cnt[g] : 0;
#pragma unroll
  for (int o = 1; o < 64; o <<= 1) {
    const int y = __shfl_up(v, o);
    if (lane >= o) v += y;
  }
  if (lane == 63) ws[w] = v;
  __syncthreads();
  if (w == 0) {
    int s = (lane < 16) ? ws[lane] : 0;
#pragma unroll
    for (int o = 1; o < 16; o <<= 1) {
      const int y = __shfl_up(s, o);
      if (lane >= o) s += y;
    }
    if (lane < 16) ws[lane] = s;
  }
  __syncthreads();
  v += (w > 0) ? ws[w - 1] : 0;
  if (g < N) cnt[g] = v;                  // in-place inclusive within chunk
  if (t == 1023) bsum[blockIdx.x] = v;
}

// fused: every block scans bsum locally (nb <= 256), then adds carry
__global__ __launch_bounds__(1024) void k_scan3(const int* __restrict__ part,
                                                const int* __restrict__ bsum,
                                                int* __restrict__ off, int N, int nb) {
  __shared__ int sbuf[256];
  const int t = threadIdx.x;
  if (t < 64) {
    int carry = 0;
    for (int base = 0; base < nb; base += 64) {
      int v = (base + t < nb) ? bsum[base + t] : 0;
#pragma unroll
      for (int o = 1; o < 64; o <<= 1) {
        const int y = __shfl_up(v, o);
        if (t >= o) v += y;
      }
      v += carry;
      if (base + t < nb) sbuf[base + t] = v;
      carry = __shfl(v, 63);
    }
  }
  __syncthreads();
  const int g = blockIdx.x * 1024 + t;
  if (g == 0) off[0] = 0;
  if (g < N) off[g + 1] = part[g] + (blockIdx.x ? sbuf[blockIdx.x - 1] : 0);
}

// ---------------- K3: scatter (no atomics; u16 dst) ---------------------------
__global__ void k_scatter(const int* __restrict__ src, const int* __restrict__ dst,
                          const int* __restrict__ off, const unsigned short* __restrict__ rank,
                          unsigned short* __restrict__ csr_dst, int E) {
  int i = blockIdx.x * blockDim.x + threadIdx.x;
  const int stride = gridDim.x * blockDim.x;
  for (; i < E; i += stride)
    csr_dst[off[src[i]] + rank[i]] = (unsigned short)dst[i];
}

// ---------------- K4: fused softmax + SpMM, excess-128 int8 -------------------
__global__ __launch_bounds__(256) void k_spmm(const uint2* __restrict__ Hq2,
    const float4* __restrict__ ssrc4, const unsigned char* __restrict__ rec,
    const int* __restrict__ off, const unsigned short* __restrict__ csr_dst,
    const float* __restrict__ bias, float* __restrict__ out, int N) {
  __shared__ float wbuf[4][8][72];   // [wave][col-block][edge], w[h]*scl[d][b]
  __shared__ int   ibuf[4][64];
  const int wv = threadIdx.x >> 6;
  const int lane = threadIdx.x & 63;
  const int n = (blockIdx.x << 2) + wv;
  if (n >= N) return;                 // wave-private LDS, no barriers
  const int hg = lane >> 4;           // head of this lane
  const int b8 = lane >> 3;           // 64-col block of this lane
  const float4 ss4 = ssrc4[n];
  float den4[4] = {};
  float acc[8] = {};
  float sw = 0.f;                     // sum of this lane's scaled weights
  const int beg = off[n], end = off[n + 1];
  for (int c0 = beg; c0 < end; c0 += 64) {
    const int cnt = min(64, end - c0);
    if (lane < cnt) {                 // -------- phase A --------
      const int d = csr_dst[c0 + lane];          // coalesced u16
      ibuf[wv][lane] = d << 6;                   // row base in uint2 units
      const float4 sd4 = *(const float4*)&rec[(size_t)d * 32];       // one line:
      const uint4  sc  = *(const uint4*)&rec[(size_t)d * 32 + 16];   // sdst+scales
      float e0 = ss4.x + sd4.x; e0 = fmaxf(e0, ALPHA * e0);
      float e1 = ss4.y + sd4.y; e1 = fmaxf(e1, ALPHA * e1);
      float e2 = ss4.z + sd4.z; e2 = fmaxf(e2, ALPHA * e2);
      float e3 = ss4.w + sd4.w; e3 = fmaxf(e3, ALPHA * e3);
      const float w0 = __expf(e0), w1 = __expf(e1), w2 = __expf(e2), w3 = __expf(e3);
      den4[0] += w0; den4[1] += w1; den4[2] += w2; den4[3] += w3;
      wbuf[wv][0][lane] = w0 * bf_lo(sc.x); wbuf[wv][1][lane] = w0 * bf_hi(sc.x);
      wbuf[wv][2][lane] = w1 * bf_lo(sc.y); wbuf[wv][3][lane] = w1 * bf_hi(sc.y);
      wbuf[wv][4][lane] = w2 * bf_lo(sc.z); wbuf[wv][5][lane] = w2 * bf_hi(sc.z);
      wbuf[wv][6][lane] = w3 * bf_lo(sc.w); wbuf[wv][7][lane] = w3 * bf_hi(sc.w);
    }
#pragma unroll 8
    for (int j = 0; j < cnt; ++j) {   // -------- phase B --------
      const float wgt = wbuf[wv][b8][j];         // LDS broadcast (scaled)
      const int db = ibuf[wv][j];                // LDS broadcast
      const uint2 q = Hq2[db + lane];            // 8B gather, 512B/row/wave
      sw += wgt;
      acc[0] = fmaf(wgt, (float)(q.x & 0xffu),         acc[0]);
      acc[1] = fmaf(wgt, (float)((q.x >> 8) & 0xffu),  acc[1]);
      acc[2] = fmaf(wgt, (float)((q.x >> 16) & 0xffu), acc[2]);
      acc[3] = fmaf(wgt, (float)(q.x >> 24),           acc[3]);
      acc[4] = fmaf(wgt, (float)(q.y & 0xffu),         acc[4]);
      acc[5] = fmaf(wgt, (float)((q.y >> 8) & 0xffu),  acc[5]);
      acc[6] = fmaf(wgt, (float)((q.y >> 16) & 0xffu), acc[6]);
      acc[7] = fmaf(wgt, (float)(q.y >> 24),           acc[7]);
    }
  }
#pragma unroll
  for (int k = 0; k < 4; ++k)
#pragma unroll
    for (int m = 1; m < 64; m <<= 1) den4[k] += __shfl_xor(den4[k], m);
  const float r = 1.f / (den4[hg] + EPS);
  const float corr = 128.f * sw;      // undo excess-128 bias
#pragma unroll
  for (int i = 0; i < 8; ++i) acc[i] = (acc[i] - corr) * r;
#pragma unroll
  for (int i = 0; i < 8; ++i) {       // sum the 4 heads (same feature at l^16,l^32)
    acc[i] += __shfl_xor(acc[i], 16);
    acc[i] += __shfl_xor(acc[i], 32);
  }
  if (lane < 16) {
    // permuted layout: acc[i] = feature 64*((lane>>3)&1) + (i&3)*16 + 2*(lane&7) + (i>>2)
    const int base = ((lane >> 3) & 1) * 64 + ((lane & 7) << 1);
#pragma unroll
    for (int k = 0; k < 4; ++k) {
      const float2 b2 = *(const float2*)&bias[base + k * 16];
      *(float2*)&out[(size_t)n * F_OUT + base + k * 16] =
          make_float2(0.25f * acc[k] + b2.x, 0.25f * acc[k + 4] + b2.y);
    }
  }
}

// ---------------- launch -------------------------------------------------------
extern "C" void kernel_launch(void* const* d_in, const int* in_sizes, int n_in,
                              void* d_out, int out_size, void* d_ws, size_t ws_size,
                              hipStream_t stream) {
  const float* H    = (const float*)d_in[0];
  const int*   ei   = (const int*)d_in[1];
  const float* W    = (const float*)d_in[2];   // [4,128,256] == [512,256]
  const float* a    = (const float*)d_in[3];   // [4,256]
  const float* bias = (const float*)d_in[4];   // [128]
  const int N = in_sizes[0] / F_IN;
  const int E = in_sizes[1] / 2;
  const int* src = ei;
  const int* dst = ei + E;

  char* ws = (char*)d_ws;
  size_t o = 0;
  auto alloc = [&](size_t bytes) -> void* {
    void* p = ws + o;
    o = (o + bytes + 255) & ~(size_t)255;
    return p;
  };
  unsigned char*  Hq  = (unsigned char*)alloc((size_t)N * COLS);        // 25.6 MB int8
  float* ssrc = (float*)alloc((size_t)N * HEADS * sizeof(float));
  unsigned char* rec = (unsigned char*)alloc((size_t)N * 32);           // 1.6 MB packed
  int*   cnt  = (int*)alloc((size_t)N * sizeof(int));
  int*   off  = (int*)alloc(((size_t)N + 1) * sizeof(int));
  unsigned short* csr = (unsigned short*)alloc((size_t)E * sizeof(unsigned short));
  unsigned short* rank = (unsigned short*)alloc((size_t)E * sizeof(unsigned short));
  const int nb = (N + 1023) / 1024;
  int*   bsum = (int*)alloc((size_t)nb * sizeof(int));

  hipMemsetAsync(cnt, 0, (size_t)N * sizeof(int), stream);

  const int nb128 = (N + 127) / 128;
  const int Tg = 4 * nb128;
  k_gemm_q<<<Tg + 1024, 256, 0, stream>>>(H, W, Hq, rec, ssrc, a, N, Tg,
                                          src, cnt, rank, E);
  k_scan1<<<nb, 1024, 0, stream>>>(cnt, bsum, N);
  k_scan3<<<nb, 1024, 0, stream>>>(cnt, bsum, off, N, nb);
  k_scatter<<<1024, 256, 0, stream>>>(src, dst, off, rank, csr, E);
  k_spmm<<<(N + 3) / 4, 256, 0, stream>>>((const uint2*)Hq, (const float4*)ssrc,
                                          rec, off, csr, bias, (float*)d_out, N);
}